// Round 13
// baseline (829.668 us; speedup 1.0000x reference)
//
#include <hip/hip_runtime.h>

#define N_NODES  200000
#define N_EDGES  600000
#define N_GRAPHS 4000
#define IN_DIM   25
#define EDGE_DIM 11
#define HIDDEN   128
#define DEPTH    4
#define BN_EPS   1e-5f

#define UB   64                   // nodes per block in update kernel
#define NBLK (N_NODES / UB)       // 3125 partial-stat rows
#define EB   128                  // edges per block in edge kernel
#define NEBLK ((N_EDGES + EB - 1) / EB)   // 4688 (last block: 64 real + 64 pad)
#define CHUNK  256
#define NCHUNK ((N_NODES + CHUNK - 1) / CHUNK)   // 782

typedef unsigned short ushortT;
typedef __attribute__((ext_vector_type(8))) short short8v;
typedef __attribute__((ext_vector_type(4))) float float4v;

__device__ __forceinline__ float lrelu(float v) { return v > 0.f ? v : 0.1f * v; }

__device__ __forceinline__ ushortT f2bf(float f) {
    unsigned u = __builtin_bit_cast(unsigned, f);
    u = (u + 0x7fffu + ((u >> 16) & 1u)) >> 16;
    return (ushortT)u;
}
__device__ __forceinline__ float bf2f(ushortT h) {
    unsigned u = ((unsigned)h) << 16;
    return __builtin_bit_cast(float, u);
}

// ================= counting sort of edges by dst (once per call) =================
__global__ void k_hist(const int* __restrict__ ei, int* __restrict__ cnt)
{
    const int e = blockIdx.x * 256 + threadIdx.x;
    if (e < N_EDGES) atomicAdd(&cnt[ei[N_EDGES + e]], 1);
}

__global__ __launch_bounds__(256) void k_chunk_sum(const int* __restrict__ cnt,
                                                   int* __restrict__ bsum)
{
    const int t = threadIdx.x;
    const int i = blockIdx.x * CHUNK + t;
    int v = (i < N_NODES) ? cnt[i] : 0;
    #pragma unroll
    for (int off = 32; off > 0; off >>= 1) v += __shfl_down(v, off);
    __shared__ int ws[4];
    if ((t & 63) == 0) ws[t >> 6] = v;
    __syncthreads();
    if (t == 0) bsum[blockIdx.x] = ws[0] + ws[1] + ws[2] + ws[3];
}

__global__ __launch_bounds__(1024) void k_scan_bsums(const int* __restrict__ bsum,
                                                     int* __restrict__ bscan)
{
    __shared__ int s[1024];
    const int t = threadIdx.x;
    const int v = (t < NCHUNK) ? bsum[t] : 0;
    s[t] = v; __syncthreads();
    for (int off = 1; off < 1024; off <<= 1) {
        const int x = (t >= off) ? s[t - off] : 0;
        __syncthreads();
        s[t] += x;
        __syncthreads();
    }
    if (t < NCHUNK) bscan[t] = s[t] - v;   // exclusive
}

__global__ __launch_bounds__(256) void k_chunk_scan(const int* __restrict__ cnt,
                                                    const int* __restrict__ bscan,
                                                    int* __restrict__ off_work)
{
    __shared__ int s[CHUNK];
    const int b = blockIdx.x, t = threadIdx.x;
    const int i = b * CHUNK + t;
    const int v = (i < N_NODES) ? cnt[i] : 0;
    s[t] = v; __syncthreads();
    for (int off = 1; off < CHUNK; off <<= 1) {
        const int x = (t >= off) ? s[t - off] : 0;
        __syncthreads();
        s[t] += x;
        __syncthreads();
    }
    if (i < N_NODES) off_work[i] = bscan[b] + s[t] - v;   // exclusive
}

__global__ void k_scatter(const int* __restrict__ ei, int* __restrict__ off_work,
                          int* __restrict__ srcS, int* __restrict__ dstS,
                          int* __restrict__ perm)
{
    const int e = blockIdx.x * 256 + threadIdx.x;
    if (e < N_EDGES) {
        const int d = ei[N_EDGES + e];
        const int pos = atomicAdd(&off_work[d], 1);
        srcS[pos] = ei[e];
        dstS[pos] = d;
        perm[pos] = e;
    }
}

// ------- pad tail + init affine (MUST run before k_flags: k_flags reads pad) -------
__global__ void k_pad_edges(int* __restrict__ srcS, int* __restrict__ dstS,
                            ushortT* __restrict__ ea16,
                            float* __restrict__ scale, float* __restrict__ shift)
{
    const int t = threadIdx.x;   // 1024 threads
    if (t < 64) { srcS[N_EDGES + t] = 0; dstS[N_EDGES + t] = N_NODES; }
    ea16[(size_t)N_EDGES * 16 + t] = 0;   // 64 rows x 16 cols = 1024 shorts
    if (t < HIDDEN) { scale[t] = 1.f; shift[t] = 0.f; }
}

// ------- merged: boundary/zero-degree flags + pool count -------
#define FLG_ENDS (NEBLK * 16)
#define FLG_TOT  (FLG_ENDS + N_NODES)
#define FLG_ALL  (FLG_TOT + N_NODES)
__global__ void k_flags(const int* __restrict__ dstS, const int* __restrict__ ecnt,
                        int* __restrict__ flag,
                        const int* __restrict__ batch, float* __restrict__ cnt)
{
    const int i = blockIdx.x * 256 + threadIdx.x;
    if (i < FLG_ENDS) {
        const int b = i >> 4, p = i & 15;
        const int pp = (p >> 1) * 16 + ((p & 1) ? 15 : 0);   // {0,15,16,31,...,112,127}
        flag[dstS[(size_t)b * EB + pp]] = 1;
    } else if (i < FLG_TOT) {
        const int n = i - FLG_ENDS;
        if (ecnt[n] == 0) flag[n] = 1;
    } else if (i < FLG_ALL) {
        const int n = i - FLG_TOT;
        atomicAdd(&cnt[batch[n]], 1.0f);
    }
}

__global__ void k_compact(const int* __restrict__ flag, int* __restrict__ zlist,
                          int* __restrict__ zcount)
{
    const int n = blockIdx.x * 256 + threadIdx.x;
    if (n < N_NODES + 1 && flag[n]) zlist[atomicAdd(zcount, 1)] = n;
}

// ---------------- prep: edge_attr (sorted order) -> padded bf16 [N_EDGES][16] ----------------
__global__ __launch_bounds__(256) void k_prep_ea(const float* __restrict__ ea,
                                                 const int* __restrict__ perm,
                                                 ushortT* __restrict__ ea16)
{
    const size_t i = (size_t)blockIdx.x * 256 + threadIdx.x;
    if (i >= (size_t)N_EDGES * 16) return;
    const int e = (int)(i >> 4), c = (int)(i & 15);
    const int pe = perm[e];
    ea16[i] = (c < EDGE_DIM) ? f2bf(ea[(size_t)pe * EDGE_DIM + c]) : (ushortT)0;
}

// ------- per-layer weight fold (BN affine folded in) + zero-rows (fused) -------
__global__ __launch_bounds__(256) void k_fold(const float* __restrict__ Wm,
                                              const float* __restrict__ bm,
                                              const float* __restrict__ Wu,
                                              const float* __restrict__ bu,
                                              const float* __restrict__ scale,
                                              const float* __restrict__ shift,
                                              ushortT* __restrict__ WmF,
                                              float*   __restrict__ bmF,
                                              ushortT* __restrict__ WuF,
                                              float*   __restrict__ buF,
                                              const int* __restrict__ zlist,
                                              const int* __restrict__ zcount,
                                              float* __restrict__ aggr)
{
    const int b = blockIdx.x, t = threadIdx.x;
    if (b < 80) {                          // W_msg fragment: 20480 elems, K padded 139->160 (k>=139 -> 0)
        const int i = b * 256 + t;
        const int j = i & 7, lane = (i >> 3) & 63, tile = i >> 9;
        const int ct = tile & 7, kt = tile >> 3;
        const int k = kt * 32 + ((lane >> 4) << 3) + j;
        const int c = ct * 16 + (lane & 15);
        float v = (k < HIDDEN + EDGE_DIM) ? Wm[k * HIDDEN + c] : 0.f;
        if (k < HIDDEN) v *= scale[k];
        WmF[i] = f2bf(v);
    } else if (b < 208) {                  // W_up fragment: 32768 elems, K = 256
        const int i = (b - 80) * 256 + t;
        const int j = i & 7, lane = (i >> 3) & 63, tile = i >> 9;
        const int ct = tile & 7, kt = tile >> 3;
        const int k = kt * 32 + ((lane >> 4) << 3) + j;
        const int c = ct * 16 + (lane & 15);
        float v = Wu[k * HIDDEN + c];
        if (k >= HIDDEN) v *= scale[k - HIDDEN];
        WuF[i] = f2bf(v);
    } else if (b == 208) {
        if (t < HIDDEN) {
            float acc = bm[t];
            for (int k = 0; k < HIDDEN; ++k) acc += shift[k] * Wm[k * HIDDEN + t];
            bmF[t] = acc;
        }
    } else if (b == 209) {
        if (t < HIDDEN) {
            float acc = bu[t];
            for (int k = 0; k < HIDDEN; ++k) acc += shift[k] * Wu[(HIDDEN + k) * HIDDEN + t];
            buF[t] = acc;
        }
    } else {                               // zero-rows role: blocks 210..465
        const int total = zcount[0] * 32;
        const float4 z = {0.f, 0.f, 0.f, 0.f};
        for (int i = (b - 210) * 256 + t; i < total; i += 256 * 256) {
            const int row = zlist[i >> 5], q = i & 31;
            reinterpret_cast<float4*>(aggr)[(size_t)row * 32 + q] = z;
        }
    }
}

// ---------------- input projection via MFMA: h16 = bf16(lrelu(x @ W_in + b_in)) ----------------
__global__ __launch_bounds__(512) void k_input_mfma(const float* __restrict__ x,
                                                    const float* __restrict__ W,
                                                    const float* __restrict__ b,
                                                    ushortT* __restrict__ hout)
{
    const int t    = threadIdx.x;
    const int wave = t >> 6, lane = t & 63;
    const int n0   = blockIdx.x * 64;

    __shared__ __align__(16) ushortT sHi[64][40];
    __shared__ __align__(16) ushortT sLo[64][40];

    for (int i = t; i < 64 * 32; i += 512) {
        const int r = i >> 5, c = i & 31;
        const float v = (c < IN_DIM) ? x[(size_t)(n0 + r) * IN_DIM + c] : 0.f;
        const ushortT hb = f2bf(v);
        sHi[r][c] = hb;
        sLo[r][c] = f2bf(v - bf2f(hb));
    }

    const int ct   = wave;
    const int col  = lane & 15;
    const int kOff = (lane >> 4) * 8;
    short8v Bhi, Blo;
    #pragma unroll
    for (int j = 0; j < 8; ++j) {
        const int k = kOff + j;
        const float wv = (k < IN_DIM) ? W[k * HIDDEN + ct * 16 + col] : 0.f;
        const ushortT hb = f2bf(wv);
        Bhi[j] = (short)hb;
        Blo[j] = (short)f2bf(wv - bf2f(hb));
    }
    __syncthreads();

    float4v acc[4];
    #pragma unroll
    for (int m = 0; m < 4; ++m) acc[m] = (float4v)(0.f);

    #pragma unroll
    for (int m = 0; m < 4; ++m) {
        const int row = m * 16 + (lane & 15);
        const short8v ahi = *reinterpret_cast<const short8v*>(&sHi[row][kOff]);
        const short8v alo = *reinterpret_cast<const short8v*>(&sLo[row][kOff]);
        acc[m] = __builtin_amdgcn_mfma_f32_16x16x32_bf16(ahi, Bhi, acc[m], 0, 0, 0);
        acc[m] = __builtin_amdgcn_mfma_f32_16x16x32_bf16(ahi, Blo, acc[m], 0, 0, 0);
        acc[m] = __builtin_amdgcn_mfma_f32_16x16x32_bf16(alo, Bhi, acc[m], 0, 0, 0);
    }

    const int r0   = (lane >> 4) * 4;
    const int ccol = ct * 16 + col;
    const float bt = b[ccol];
    #pragma unroll
    for (int m = 0; m < 4; ++m) {
        #pragma unroll
        for (int j = 0; j < 4; ++j) {
            hout[(size_t)(n0 + m * 16 + r0 + j) * HIDDEN + ccol] = f2bf(lrelu(acc[m][j] + bt));
        }
    }
}

// ------- fused edge message MFMA GEMM + lrelu + segmented-reduce scatter -------
// Stride 144 (was 168): the 16 zero-pad cols are dropped because Wf rows k>=139
// are zero, so the kt=4 over-read (next row's finite h16 / guard tail) contributes
// finite*0 = 0. LDS: 128*144*2 + 64 guard + sSrc + sDst = 37952B -> 4 blocks/CU.
__global__ __launch_bounds__(512) void k_edge_mfma(const ushortT* __restrict__ h16,
                                                   const int*     __restrict__ srcS,
                                                   const int*     __restrict__ dstS,
                                                   const ushortT* __restrict__ ea16,
                                                   const ushortT* __restrict__ Wf,
                                                   const float*   __restrict__ bmsg,
                                                   float*         __restrict__ aggr)
{
    const int t    = threadIdx.x;
    const int wave = t >> 6, lane = t & 63;
    const int e0   = blockIdx.x * EB;

    __shared__ __align__(16) unsigned char smem[EB * 144 * 2 + 64];  // 36928B (+guard)
    ushortT (*sA)[144]   = reinterpret_cast<ushortT (*)[144]>(smem);
    float   (*sMsg)[132] = reinterpret_cast<float (*)[132]>(smem);   // 64x132 fp32 = 33792B alias
    __shared__ int sSrc[EB];
    __shared__ int sDst[EB];

    // B fragments in registers: wave owns ct = wave (5 loads, reused 8x)
    const int ct = wave;
    short8v B[5];
    const short8v* wp = reinterpret_cast<const short8v*>(Wf);
    #pragma unroll
    for (int kt = 0; kt < 5; ++kt) B[kt] = wp[(size_t)(kt * 8 + ct) * 64 + lane];

    if (t < EB) { sSrc[t] = srcS[e0 + t]; sDst[t] = dstS[e0 + t]; }
    __syncthreads();

    // stage h16 rows: 128 edges x 16 uint4 (cols 0..127)
    for (int i = t; i < EB * 16; i += 512) {
        const int e = i >> 4, q = i & 15;
        const uint4 v = reinterpret_cast<const uint4*>(h16)[(size_t)sSrc[e] * 16 + q];
        *reinterpret_cast<uint4*>(&sA[e][q * 8]) = v;
    }
    // stage compact edge_attr (cols 128..143; cols 139..143 are zeros from prep)
    if (t < EB * 2) {
        const int e = t >> 1, q = t & 1;
        const uint4 v = reinterpret_cast<const uint4*>(ea16)[((size_t)(e0 + e)) * 2 + q];
        *reinterpret_cast<uint4*>(&sA[e][128 + q * 8]) = v;
    }
    __syncthreads();

    float4v acc[8];
    #pragma unroll
    for (int m = 0; m < 8; ++m) acc[m] = (float4v)(0.f);

    const int kOff = (lane >> 4) * 8;
    #pragma unroll
    for (int m = 0; m < 8; ++m) {
        const int row = m * 16 + (lane & 15);
        #pragma unroll
        for (int kt = 0; kt < 5; ++kt) {
            const short8v a = *reinterpret_cast<const short8v*>(&sA[row][kt * 32 + kOff]);
            acc[m] = __builtin_amdgcn_mfma_f32_16x16x32_bf16(a, B[kt], acc[m], 0, 0, 0);
        }
    }
    __syncthreads();   // all waves done reading sA

    const int col = lane & 15;
    const int r0  = (lane >> 4) * 4;
    const float bt = bmsg[ct * 16 + col];
    const int c   = t & 127;
    const int g   = t >> 7;           // 0..3: which 16-row group within the 64-row phase

    #pragma unroll
    for (int p = 0; p < 2; ++p) {
        // bias + lrelu -> LDS for rows [p*64, p*64+64)
        #pragma unroll
        for (int mm = 0; mm < 4; ++mm) {
            const int m = p * 4 + mm;
            #pragma unroll
            for (int j = 0; j < 4; ++j) {
                sMsg[mm * 16 + r0 + j][ct * 16 + col] = lrelu(acc[m][j] + bt);
            }
        }
        __syncthreads();
        // column-parallel segmented reduce over this thread's 16-row group.
        // Interior runs: complete sums -> plain store (stale aggr ok).
        // Boundary runs: atomicAdd into pre-zeroed rows.
        const int base = p * 64 + g * 16;
        float a = 0.f;
        int cur = sDst[base];
        bool atStart = true;
        for (int i = 0; i < 16; ++i) {
            const int e = base + i;
            const int d = sDst[e];
            if (d != cur) {
                if (atStart) atomicAdd(&aggr[(size_t)cur * HIDDEN + c], a);
                else         aggr[(size_t)cur * HIDDEN + c] = a;
                atStart = false; cur = d; a = 0.f;
            }
            a += sMsg[e - p * 64][c];
        }
        atomicAdd(&aggr[(size_t)cur * HIDDEN + c], a);
        __syncthreads();
    }
}

// ------- update MFMA GEMM: out = relu(cat[aggr, h16] @ W_up' + b_up') -------
__global__ __launch_bounds__(512) void k_update_mfma(const float*   __restrict__ aggr,
                                                     const ushortT* __restrict__ h16,
                                                     const ushortT* __restrict__ Wf,
                                                     const float*   __restrict__ bup,
                                                     ushortT*       __restrict__ hout,
                                                     float*         __restrict__ p_sum,
                                                     float*         __restrict__ p_sumsq)
{
    const int t    = threadIdx.x;
    const int wave = t >> 6, lane = t & 63;
    const int n0   = blockIdx.x * UB;

    __shared__ __align__(16) ushortT sA[UB][264];   // hi(aggr) 0..127, h16 128..255 (33792B)
    __shared__ __align__(16) ushortT sLo[UB][136];  // lo(aggr) (17408B)

    const int ct = wave;
    short8v Bh[8];
    const short8v* wp = reinterpret_cast<const short8v*>(Wf);
    #pragma unroll
    for (int kt = 0; kt < 8; ++kt) Bh[kt] = wp[(size_t)(kt * 8 + ct) * 64 + lane];

    // stage aggr fp32 -> hi/lo bf16 split
    for (int i = t; i < UB * 32; i += 512) {
        const int n = i >> 5, q = i & 31;
        const float4 v = reinterpret_cast<const float4*>(aggr)[(size_t)(n0 + n) * 32 + q];
        union { ushortT s[4]; uint2 u; } hi, lo;
        #pragma unroll
        for (int j = 0; j < 4; ++j) {
            const float f = (&v.x)[j];
            const ushortT hb = f2bf(f);
            hi.s[j] = hb;
            lo.s[j] = f2bf(f - bf2f(hb));
        }
        *reinterpret_cast<uint2*>(&sA[n][q * 4])  = hi.u;
        *reinterpret_cast<uint2*>(&sLo[n][q * 4]) = lo.u;
    }
    // stage h16 (cols 128..255)
    for (int i = t; i < UB * 16; i += 512) {
        const int n = i >> 4, q = i & 15;
        const uint4 v = reinterpret_cast<const uint4*>(h16)[(size_t)(n0 + n) * 16 + q];
        *reinterpret_cast<uint4*>(&sA[n][128 + q * 8]) = v;
    }
    __syncthreads();

    float4v acc[4];
    #pragma unroll
    for (int m = 0; m < 4; ++m) acc[m] = (float4v)(0.f);

    const int kOff = (lane >> 4) * 8;
    #pragma unroll
    for (int m = 0; m < 4; ++m) {
        const int row = m * 16 + (lane & 15);
        #pragma unroll
        for (int kt = 0; kt < 8; ++kt) {
            const short8v a = *reinterpret_cast<const short8v*>(&sA[row][kt * 32 + kOff]);
            acc[m] = __builtin_amdgcn_mfma_f32_16x16x32_bf16(a, Bh[kt], acc[m], 0, 0, 0);
        }
        #pragma unroll
        for (int kt = 0; kt < 4; ++kt) {   // lo correction over aggr half; W rows identical
            const short8v a = *reinterpret_cast<const short8v*>(&sLo[row][kt * 32 + kOff]);
            acc[m] = __builtin_amdgcn_mfma_f32_16x16x32_bf16(a, Bh[kt], acc[m], 0, 0, 0);
        }
    }

    // epilogue: bias + relu, write bf16 raw out; per-wave column stats (exclusive cols)
    const int col  = lane & 15;
    const int r0   = (lane >> 4) * 4;
    const int ccol = ct * 16 + col;
    const float bt = bup[ccol];
    float s = 0.f, q = 0.f;
    #pragma unroll
    for (int m = 0; m < 4; ++m) {
        #pragma unroll
        for (int j = 0; j < 4; ++j) {
            const float v = fmaxf(acc[m][j] + bt, 0.f);
            s += v; q += v * v;
            hout[(size_t)(n0 + m * 16 + r0 + j) * HIDDEN + ccol] = f2bf(v);
        }
    }
    s += __shfl_xor(s, 16); s += __shfl_xor(s, 32);
    q += __shfl_xor(q, 16); q += __shfl_xor(q, 32);
    if (lane < 16) {
        p_sum  [(size_t)blockIdx.x * HIDDEN + ccol] = s;
        p_sumsq[(size_t)blockIdx.x * HIDDEN + ccol] = q;
    }
}

// ------- BN reduce: one block per feature -------
__global__ __launch_bounds__(256) void k_bn_reduce(const float* __restrict__ p_sum,
                                                   const float* __restrict__ p_sumsq,
                                                   const float* __restrict__ gamma,
                                                   const float* __restrict__ beta,
                                                   float* __restrict__ scale,
                                                   float* __restrict__ shift)
{
    const int c = blockIdx.x, t = threadIdx.x;
    float s = 0.f, q = 0.f;
    for (int i = t; i < NBLK; i += 256) {
        s += p_sum  [(size_t)i * HIDDEN + c];
        q += p_sumsq[(size_t)i * HIDDEN + c];
    }
    #pragma unroll
    for (int off = 32; off > 0; off >>= 1) {
        s += __shfl_down(s, off);
        q += __shfl_down(q, off);
    }
    __shared__ float ls[4], lq[4];
    const int w = t >> 6;
    if ((t & 63) == 0) { ls[w] = s; lq[w] = q; }
    __syncthreads();
    if (t == 0) {
        s = ls[0] + ls[1] + ls[2] + ls[3];
        q = lq[0] + lq[1] + lq[2] + lq[3];
        const float mu  = s * (1.f / N_NODES);
        const float var = q * (1.f / N_NODES) - mu * mu;
        const float sc  = gamma[c] * rsqrtf(var + BN_EPS);
        scale[c] = sc;
        shift[c] = beta[c] - mu * sc;
    }
}

// ------- mean pool over graphs (applies final BN affine inline) -------
__global__ __launch_bounds__(128) void k_pool_sum(const ushortT* __restrict__ h16,
                                                  const int* __restrict__ batch,
                                                  const float* __restrict__ scale,
                                                  const float* __restrict__ shift,
                                                  float* __restrict__ pool)
{
    const int t  = threadIdx.x;
    const int n0 = blockIdx.x * 16;
    __shared__ int sb[16];
    if (t < 16) sb[t] = batch[n0 + t];
    __syncthreads();
    const float sc = scale[t], sh = shift[t];
    int g = sb[0];
    float acc = 0.f;
    for (int j = 0; j < 16; ++j) {
        const float v = sc * bf2f(h16[(size_t)(n0 + j) * HIDDEN + t]) + sh;
        if (sb[j] != g) {
            atomicAdd(&pool[(size_t)g * HIDDEN + t], acc);
            g = sb[j];
            acc = v;
        } else {
            acc += v;
        }
    }
    atomicAdd(&pool[(size_t)g * HIDDEN + t], acc);
}

__global__ void k_pool_div(const float* __restrict__ pool,
                           const float* __restrict__ cnt,
                           float* __restrict__ out)
{
    const int i = blockIdx.x * 256 + threadIdx.x;
    if (i < N_GRAPHS * HIDDEN) {
        const int g = i >> 7;
        out[i] = pool[i] / fmaxf(cnt[g], 1.0f);
    }
}

extern "C" void kernel_launch(void* const* d_in, const int* in_sizes, int n_in,
                              void* d_out, int out_size, void* d_ws, size_t ws_size,
                              hipStream_t stream)
{
    const float* x     = (const float*)d_in[0];
    const int*   ei    = (const int*)  d_in[1];
    const float* ea    = (const float*)d_in[2];
    const int*   batch = (const int*)  d_in[3];
    const float* W_in  = (const float*)d_in[4];
    const float* b_in  = (const float*)d_in[5];
    const float* W_msg = (const float*)d_in[6];
    const float* b_msg = (const float*)d_in[7];
    const float* W_up  = (const float*)d_in[8];
    const float* b_up  = (const float*)d_in[9];
    const float* gamma = (const float*)d_in[10];
    const float* beta  = (const float*)d_in[11];
    float* out = (float*)d_out;

    // ---- workspace layout (zero-init region kept CONTIGUOUS: ecnt..cnt) ----
    float*   aggr  = (float*)d_ws;                                   // (N+1)*128 fp32 (dummy row)
    ushortT* hA    = (ushortT*)(aggr + (size_t)(N_NODES + 1) * HIDDEN);  // N*128 bf16
    ushortT* hB    = hA + (size_t)N_NODES * HIDDEN;                  // N*128 bf16
    ushortT* ea16  = hB + (size_t)N_NODES * HIDDEN;                  // (E+64)*16 bf16
    ushortT* wmsgfA = ea16 + (size_t)(N_EDGES + 64) * 16;            // 20480
    ushortT* wupfA  = wmsgfA + 20480;                                // 32768
    float*   biasM  = (float*)(wupfA + 32768);                       // 128
    float*   biasU  = biasM + HIDDEN;                                // 128
    float*   bn_scale = biasU + HIDDEN;                              // 128
    float*   bn_shift = bn_scale + HIDDEN;                           // 128
    float*   p_sum    = bn_shift + HIDDEN;                           // NBLK*128
    float*   p_sumsq  = p_sum + (size_t)HIDDEN * NBLK;               // NBLK*128
    // ---- contiguous zero-init region ----
    int*     ecnt     = (int*)(p_sumsq + (size_t)HIDDEN * NBLK);     // N
    int*     flag     = ecnt + N_NODES;                              // N+1
    int*     zcount   = flag + (N_NODES + 1);                        // 1
    float*   pool     = (float*)(zcount + 1);                        // G*128
    float*   cnt      = pool + (size_t)N_GRAPHS * HIDDEN;            // G
    // ---- end zero-init region ----
    int*     off_work = (int*)(cnt + N_GRAPHS);                      // N
    int*     bsum     = off_work + N_NODES;                          // 1024
    int*     bscan    = bsum + 1024;                                 // 1024
    int*     srcS     = bscan + 1024;                                // E+64
    int*     dstS     = srcS + (N_EDGES + 64);                       // E+64
    int*     perm     = dstS + (N_EDGES + 64);                       // E
    int*     zlist    = perm + N_EDGES;                              // N+1

    const size_t zero_bytes = ((size_t)N_NODES + (N_NODES + 1) + 1
                               + (size_t)N_GRAPHS * HIDDEN + N_GRAPHS) * 4;

    // ---- edge sort by dst + pad + needs-zero set (once; edge_index constant) ----
    hipMemsetAsync(ecnt, 0, zero_bytes, stream);   // ecnt, flag, zcount, pool, cnt
    k_hist<<<(N_EDGES + 255) / 256, 256, 0, stream>>>(ei, ecnt);
    k_chunk_sum<<<NCHUNK, 256, 0, stream>>>(ecnt, bsum);
    k_scan_bsums<<<1, 1024, 0, stream>>>(bsum, bscan);
    k_chunk_scan<<<NCHUNK, 256, 0, stream>>>(ecnt, bscan, off_work);
    k_scatter<<<(N_EDGES + 255) / 256, 256, 0, stream>>>(ei, off_work, srcS, dstS, perm);
    k_pad_edges<<<1, 1024, 0, stream>>>(srcS, dstS, ea16, bn_scale, bn_shift); // BEFORE k_flags
    k_flags<<<(FLG_ALL + 255) / 256, 256, 0, stream>>>(dstS, ecnt, flag, batch, cnt);
    k_compact<<<(N_NODES + 256) / 256, 256, 0, stream>>>(flag, zlist, zcount);

    // ---- one-time prep ----
    k_prep_ea<<<(N_EDGES * 16 + 255) / 256, 256, 0, stream>>>(ea, perm, ea16);
    k_input_mfma<<<N_NODES / 64, 512, 0, stream>>>(x, W_in, b_in, hA);

    ushortT* hcur = hA;
    ushortT* hnext = hB;
    for (int d = 0; d < DEPTH; ++d) {
        k_fold<<<466, 256, 0, stream>>>(
            W_msg + (size_t)d * (HIDDEN + EDGE_DIM) * HIDDEN, b_msg + (size_t)d * HIDDEN,
            W_up + (size_t)d * 2 * HIDDEN * HIDDEN, b_up + (size_t)d * HIDDEN,
            bn_scale, bn_shift, wmsgfA, biasM, wupfA, biasU,
            zlist, zcount, aggr);
        k_edge_mfma<<<NEBLK, 512, 0, stream>>>(
            hcur, srcS, dstS, ea16, wmsgfA, biasM, aggr);
        k_update_mfma<<<N_NODES / UB, 512, 0, stream>>>(
            aggr, hcur, wupfA, biasU, hnext, p_sum, p_sumsq);
        k_bn_reduce<<<HIDDEN, 256, 0, stream>>>(p_sum, p_sumsq,
                                                gamma + (size_t)d * HIDDEN,
                                                beta + (size_t)d * HIDDEN,
                                                bn_scale, bn_shift);
        ushortT* tmp = hcur; hcur = hnext; hnext = tmp;
    }

    k_pool_sum<<<N_NODES / 16, 128, 0, stream>>>(hcur, batch, bn_scale, bn_shift, pool);
    k_pool_div<<<(N_GRAPHS * HIDDEN + 255) / 256, 256, 0, stream>>>(pool, cnt, out);
}

// Round 14
// 792.445 us; speedup vs baseline: 1.0470x; 1.0470x over previous
//
#include <hip/hip_runtime.h>

#define N_NODES  200000
#define N_EDGES  600000
#define N_GRAPHS 4000
#define IN_DIM   25
#define EDGE_DIM 11
#define HIDDEN   128
#define DEPTH    4
#define BN_EPS   1e-5f

#define UB   64                   // nodes per block in update kernel
#define NBLK (N_NODES / UB)       // 3125 partial-stat rows
#define EB   128                  // edges per block in edge kernel
#define NEBLK ((N_EDGES + EB - 1) / EB)   // 4688 (last block: 64 real + 64 pad)
#define CHUNK  256
#define NCHUNK ((N_NODES + CHUNK - 1) / CHUNK)   // 782

typedef unsigned short ushortT;
typedef __attribute__((ext_vector_type(8))) short short8v;
typedef __attribute__((ext_vector_type(4))) float float4v;

__device__ __forceinline__ float lrelu(float v) { return v > 0.f ? v : 0.1f * v; }

__device__ __forceinline__ ushortT f2bf(float f) {
    unsigned u = __builtin_bit_cast(unsigned, f);
    u = (u + 0x7fffu + ((u >> 16) & 1u)) >> 16;
    return (ushortT)u;
}
__device__ __forceinline__ float bf2f(ushortT h) {
    unsigned u = ((unsigned)h) << 16;
    return __builtin_bit_cast(float, u);
}

// ================= counting sort of edges by dst (once per call) =================
__global__ void k_hist(const int* __restrict__ ei, int* __restrict__ cnt)
{
    const int e = blockIdx.x * 256 + threadIdx.x;
    if (e < N_EDGES) atomicAdd(&cnt[ei[N_EDGES + e]], 1);
}

__global__ __launch_bounds__(256) void k_chunk_sum(const int* __restrict__ cnt,
                                                   int* __restrict__ bsum)
{
    const int t = threadIdx.x;
    const int i = blockIdx.x * CHUNK + t;
    int v = (i < N_NODES) ? cnt[i] : 0;
    #pragma unroll
    for (int off = 32; off > 0; off >>= 1) v += __shfl_down(v, off);
    __shared__ int ws[4];
    if ((t & 63) == 0) ws[t >> 6] = v;
    __syncthreads();
    if (t == 0) bsum[blockIdx.x] = ws[0] + ws[1] + ws[2] + ws[3];
}

__global__ __launch_bounds__(1024) void k_scan_bsums(const int* __restrict__ bsum,
                                                     int* __restrict__ bscan)
{
    __shared__ int s[1024];
    const int t = threadIdx.x;
    const int v = (t < NCHUNK) ? bsum[t] : 0;
    s[t] = v; __syncthreads();
    for (int off = 1; off < 1024; off <<= 1) {
        const int x = (t >= off) ? s[t - off] : 0;
        __syncthreads();
        s[t] += x;
        __syncthreads();
    }
    if (t < NCHUNK) bscan[t] = s[t] - v;   // exclusive
}

__global__ __launch_bounds__(256) void k_chunk_scan(const int* __restrict__ cnt,
                                                    const int* __restrict__ bscan,
                                                    int* __restrict__ off_work)
{
    __shared__ int s[CHUNK];
    const int b = blockIdx.x, t = threadIdx.x;
    const int i = b * CHUNK + t;
    const int v = (i < N_NODES) ? cnt[i] : 0;
    s[t] = v; __syncthreads();
    for (int off = 1; off < CHUNK; off <<= 1) {
        const int x = (t >= off) ? s[t - off] : 0;
        __syncthreads();
        s[t] += x;
        __syncthreads();
    }
    if (i < N_NODES) off_work[i] = bscan[b] + s[t] - v;   // exclusive
}

__global__ void k_scatter(const int* __restrict__ ei, int* __restrict__ off_work,
                          int* __restrict__ srcS, int* __restrict__ dstS,
                          int* __restrict__ perm)
{
    const int e = blockIdx.x * 256 + threadIdx.x;
    if (e < N_EDGES) {
        const int d = ei[N_EDGES + e];
        const int pos = atomicAdd(&off_work[d], 1);
        srcS[pos] = ei[e];
        dstS[pos] = d;
        perm[pos] = e;
    }
}

// ------- pad tail + init affine (MUST run before k_flags: k_flags reads pad) -------
__global__ void k_pad_edges(int* __restrict__ srcS, int* __restrict__ dstS,
                            ushortT* __restrict__ ea16,
                            float* __restrict__ scale, float* __restrict__ shift)
{
    const int t = threadIdx.x;   // 1024 threads
    if (t < 64) { srcS[N_EDGES + t] = 0; dstS[N_EDGES + t] = N_NODES; }
    ea16[(size_t)N_EDGES * 16 + t] = 0;   // 64 rows x 16 cols = 1024 shorts
    if (t < HIDDEN) { scale[t] = 1.f; shift[t] = 0.f; }
}

// ------- merged: boundary/zero-degree flags + pool count -------
#define FLG_ENDS (NEBLK * 16)
#define FLG_TOT  (FLG_ENDS + N_NODES)
#define FLG_ALL  (FLG_TOT + N_NODES)
__global__ void k_flags(const int* __restrict__ dstS, const int* __restrict__ ecnt,
                        int* __restrict__ flag,
                        const int* __restrict__ batch, float* __restrict__ cnt)
{
    const int i = blockIdx.x * 256 + threadIdx.x;
    if (i < FLG_ENDS) {
        const int b = i >> 4, p = i & 15;
        const int pp = (p >> 1) * 16 + ((p & 1) ? 15 : 0);   // {0,15,16,31,...,112,127}
        flag[dstS[(size_t)b * EB + pp]] = 1;
    } else if (i < FLG_TOT) {
        const int n = i - FLG_ENDS;
        if (ecnt[n] == 0) flag[n] = 1;
    } else if (i < FLG_ALL) {
        const int n = i - FLG_TOT;
        atomicAdd(&cnt[batch[n]], 1.0f);
    }
}

__global__ void k_compact(const int* __restrict__ flag, int* __restrict__ zlist,
                          int* __restrict__ zcount)
{
    const int n = blockIdx.x * 256 + threadIdx.x;
    if (n < N_NODES + 1 && flag[n]) zlist[atomicAdd(zcount, 1)] = n;
}

// ---------------- prep: edge_attr (sorted order) -> padded bf16 [N_EDGES][16] ----------------
__global__ __launch_bounds__(256) void k_prep_ea(const float* __restrict__ ea,
                                                 const int* __restrict__ perm,
                                                 ushortT* __restrict__ ea16)
{
    const size_t i = (size_t)blockIdx.x * 256 + threadIdx.x;
    if (i >= (size_t)N_EDGES * 16) return;
    const int e = (int)(i >> 4), c = (int)(i & 15);
    const int pe = perm[e];
    ea16[i] = (c < EDGE_DIM) ? f2bf(ea[(size_t)pe * EDGE_DIM + c]) : (ushortT)0;
}

// ------- per-layer weight fold (BN affine folded in) + zero-rows (fused) -------
__global__ __launch_bounds__(256) void k_fold(const float* __restrict__ Wm,
                                              const float* __restrict__ bm,
                                              const float* __restrict__ Wu,
                                              const float* __restrict__ bu,
                                              const float* __restrict__ scale,
                                              const float* __restrict__ shift,
                                              ushortT* __restrict__ WmF,
                                              float*   __restrict__ bmF,
                                              ushortT* __restrict__ WuF,
                                              float*   __restrict__ buF,
                                              const int* __restrict__ zlist,
                                              const int* __restrict__ zcount,
                                              float* __restrict__ aggr)
{
    const int b = blockIdx.x, t = threadIdx.x;
    if (b < 80) {                          // W_msg fragment: 20480 elems, K padded 139->160
        const int i = b * 256 + t;
        const int j = i & 7, lane = (i >> 3) & 63, tile = i >> 9;
        const int ct = tile & 7, kt = tile >> 3;
        const int k = kt * 32 + ((lane >> 4) << 3) + j;
        const int c = ct * 16 + (lane & 15);
        float v = (k < HIDDEN + EDGE_DIM) ? Wm[k * HIDDEN + c] : 0.f;
        if (k < HIDDEN) v *= scale[k];
        WmF[i] = f2bf(v);
    } else if (b < 208) {                  // W_up fragment: 32768 elems, K = 256
        const int i = (b - 80) * 256 + t;
        const int j = i & 7, lane = (i >> 3) & 63, tile = i >> 9;
        const int ct = tile & 7, kt = tile >> 3;
        const int k = kt * 32 + ((lane >> 4) << 3) + j;
        const int c = ct * 16 + (lane & 15);
        float v = Wu[k * HIDDEN + c];
        if (k >= HIDDEN) v *= scale[k - HIDDEN];
        WuF[i] = f2bf(v);
    } else if (b == 208) {
        if (t < HIDDEN) {
            float acc = bm[t];
            for (int k = 0; k < HIDDEN; ++k) acc += shift[k] * Wm[k * HIDDEN + t];
            bmF[t] = acc;
        }
    } else if (b == 209) {
        if (t < HIDDEN) {
            float acc = bu[t];
            for (int k = 0; k < HIDDEN; ++k) acc += shift[k] * Wu[(HIDDEN + k) * HIDDEN + t];
            buF[t] = acc;
        }
    } else {                               // zero-rows role: blocks 210..465
        const int total = zcount[0] * 32;
        const float4 z = {0.f, 0.f, 0.f, 0.f};
        for (int i = (b - 210) * 256 + t; i < total; i += 256 * 256) {
            const int row = zlist[i >> 5], q = i & 31;
            reinterpret_cast<float4*>(aggr)[(size_t)row * 32 + q] = z;
        }
    }
}

// ---------------- input projection via MFMA: h16 = bf16(lrelu(x @ W_in + b_in)) ----------------
__global__ __launch_bounds__(512) void k_input_mfma(const float* __restrict__ x,
                                                    const float* __restrict__ W,
                                                    const float* __restrict__ b,
                                                    ushortT* __restrict__ hout)
{
    const int t    = threadIdx.x;
    const int wave = t >> 6, lane = t & 63;
    const int n0   = blockIdx.x * 64;

    __shared__ __align__(16) ushortT sHi[64][40];
    __shared__ __align__(16) ushortT sLo[64][40];

    for (int i = t; i < 64 * 32; i += 512) {
        const int r = i >> 5, c = i & 31;
        const float v = (c < IN_DIM) ? x[(size_t)(n0 + r) * IN_DIM + c] : 0.f;
        const ushortT hb = f2bf(v);
        sHi[r][c] = hb;
        sLo[r][c] = f2bf(v - bf2f(hb));
    }

    const int ct   = wave;
    const int col  = lane & 15;
    const int kOff = (lane >> 4) * 8;
    short8v Bhi, Blo;
    #pragma unroll
    for (int j = 0; j < 8; ++j) {
        const int k = kOff + j;
        const float wv = (k < IN_DIM) ? W[k * HIDDEN + ct * 16 + col] : 0.f;
        const ushortT hb = f2bf(wv);
        Bhi[j] = (short)hb;
        Blo[j] = (short)f2bf(wv - bf2f(hb));
    }
    __syncthreads();

    float4v acc[4];
    #pragma unroll
    for (int m = 0; m < 4; ++m) acc[m] = (float4v)(0.f);

    #pragma unroll
    for (int m = 0; m < 4; ++m) {
        const int row = m * 16 + (lane & 15);
        const short8v ahi = *reinterpret_cast<const short8v*>(&sHi[row][kOff]);
        const short8v alo = *reinterpret_cast<const short8v*>(&sLo[row][kOff]);
        acc[m] = __builtin_amdgcn_mfma_f32_16x16x32_bf16(ahi, Bhi, acc[m], 0, 0, 0);
        acc[m] = __builtin_amdgcn_mfma_f32_16x16x32_bf16(ahi, Blo, acc[m], 0, 0, 0);
        acc[m] = __builtin_amdgcn_mfma_f32_16x16x32_bf16(alo, Bhi, acc[m], 0, 0, 0);
    }

    const int r0   = (lane >> 4) * 4;
    const int ccol = ct * 16 + col;
    const float bt = b[ccol];
    #pragma unroll
    for (int m = 0; m < 4; ++m) {
        #pragma unroll
        for (int j = 0; j < 4; ++j) {
            hout[(size_t)(n0 + m * 16 + r0 + j) * HIDDEN + ccol] = f2bf(lrelu(acc[m][j] + bt));
        }
    }
}

// ------- fused edge message MFMA GEMM + lrelu + segmented-reduce scatter -------
// (R12-verified best: 128 edges/block, 8 waves, sA stride 168 + zero-filled pad cols,
// sSrc/sDst staged in LDS, sMsg aliases dead A-tile; 77us @ Occ 56%.)
__global__ __launch_bounds__(512) void k_edge_mfma(const ushortT* __restrict__ h16,
                                                   const int*     __restrict__ srcS,
                                                   const int*     __restrict__ dstS,
                                                   const ushortT* __restrict__ ea16,
                                                   const ushortT* __restrict__ Wf,
                                                   const float*   __restrict__ bmsg,
                                                   float*         __restrict__ aggr)
{
    const int t    = threadIdx.x;
    const int wave = t >> 6, lane = t & 63;
    const int e0   = blockIdx.x * EB;

    __shared__ __align__(16) unsigned char smem[EB * 168 * 2];      // 43008B A-tile
    ushortT (*sA)[168]   = reinterpret_cast<ushortT (*)[168]>(smem);
    float   (*sMsg)[132] = reinterpret_cast<float (*)[132]>(smem);  // 64x132 fp32 alias
    __shared__ int sSrc[EB];
    __shared__ int sDst[EB];

    // B fragments in registers: wave owns ct = wave (5 loads, reused 8x)
    const int ct = wave;
    short8v B[5];
    const short8v* wp = reinterpret_cast<const short8v*>(Wf);
    #pragma unroll
    for (int kt = 0; kt < 5; ++kt) B[kt] = wp[(size_t)(kt * 8 + ct) * 64 + lane];

    if (t < EB) { sSrc[t] = srcS[e0 + t]; sDst[t] = dstS[e0 + t]; }
    __syncthreads();

    // stage h16 rows: 128 edges x 16 uint4 (cols 0..127)
    for (int i = t; i < EB * 16; i += 512) {
        const int e = i >> 4, q = i & 15;
        const uint4 v = reinterpret_cast<const uint4*>(h16)[(size_t)sSrc[e] * 16 + q];
        *reinterpret_cast<uint4*>(&sA[e][q * 8]) = v;
    }
    // stage compact edge_attr (cols 128..143) and zero cols 144..159
    if (t < EB * 2) {
        const int e = t >> 1, q = t & 1;
        const uint4 v = reinterpret_cast<const uint4*>(ea16)[((size_t)(e0 + e)) * 2 + q];
        *reinterpret_cast<uint4*>(&sA[e][128 + q * 8]) = v;
        const uint4 z = {0u, 0u, 0u, 0u};
        *reinterpret_cast<uint4*>(&sA[e][144 + q * 8]) = z;
    }
    __syncthreads();

    float4v acc[8];
    #pragma unroll
    for (int m = 0; m < 8; ++m) acc[m] = (float4v)(0.f);

    const int kOff = (lane >> 4) * 8;
    #pragma unroll
    for (int m = 0; m < 8; ++m) {
        const int row = m * 16 + (lane & 15);
        #pragma unroll
        for (int kt = 0; kt < 5; ++kt) {
            const short8v a = *reinterpret_cast<const short8v*>(&sA[row][kt * 32 + kOff]);
            acc[m] = __builtin_amdgcn_mfma_f32_16x16x32_bf16(a, B[kt], acc[m], 0, 0, 0);
        }
    }
    __syncthreads();   // all waves done reading sA

    const int col = lane & 15;
    const int r0  = (lane >> 4) * 4;
    const float bt = bmsg[ct * 16 + col];
    const int c   = t & 127;
    const int g   = t >> 7;           // 0..3: which 16-row group within the 64-row phase

    #pragma unroll
    for (int p = 0; p < 2; ++p) {
        // bias + lrelu -> LDS for rows [p*64, p*64+64)
        #pragma unroll
        for (int mm = 0; mm < 4; ++mm) {
            const int m = p * 4 + mm;
            #pragma unroll
            for (int j = 0; j < 4; ++j) {
                sMsg[mm * 16 + r0 + j][ct * 16 + col] = lrelu(acc[m][j] + bt);
            }
        }
        __syncthreads();
        // column-parallel segmented reduce over this thread's 16-row group.
        // Interior runs: complete sums -> plain store (stale aggr ok).
        // Boundary runs: atomicAdd into pre-zeroed rows.
        const int base = p * 64 + g * 16;
        float a = 0.f;
        int cur = sDst[base];
        bool atStart = true;
        for (int i = 0; i < 16; ++i) {
            const int e = base + i;
            const int d = sDst[e];
            if (d != cur) {
                if (atStart) atomicAdd(&aggr[(size_t)cur * HIDDEN + c], a);
                else         aggr[(size_t)cur * HIDDEN + c] = a;
                atStart = false; cur = d; a = 0.f;
            }
            a += sMsg[e - p * 64][c];
        }
        atomicAdd(&aggr[(size_t)cur * HIDDEN + c], a);
        __syncthreads();
    }
}

// ------- update MFMA GEMM: out = relu(cat[aggr, h16] @ W_up' + b_up') -------
__global__ __launch_bounds__(512) void k_update_mfma(const float*   __restrict__ aggr,
                                                     const ushortT* __restrict__ h16,
                                                     const ushortT* __restrict__ Wf,
                                                     const float*   __restrict__ bup,
                                                     ushortT*       __restrict__ hout,
                                                     float*         __restrict__ p_sum,
                                                     float*         __restrict__ p_sumsq)
{
    const int t    = threadIdx.x;
    const int wave = t >> 6, lane = t & 63;
    const int n0   = blockIdx.x * UB;

    __shared__ __align__(16) ushortT sA[UB][264];   // hi(aggr) 0..127, h16 128..255 (33792B)
    __shared__ __align__(16) ushortT sLo[UB][136];  // lo(aggr) (17408B)

    const int ct = wave;
    short8v Bh[8];
    const short8v* wp = reinterpret_cast<const short8v*>(Wf);
    #pragma unroll
    for (int kt = 0; kt < 8; ++kt) Bh[kt] = wp[(size_t)(kt * 8 + ct) * 64 + lane];

    // stage aggr fp32 -> hi/lo bf16 split
    for (int i = t; i < UB * 32; i += 512) {
        const int n = i >> 5, q = i & 31;
        const float4 v = reinterpret_cast<const float4*>(aggr)[(size_t)(n0 + n) * 32 + q];
        union { ushortT s[4]; uint2 u; } hi, lo;
        #pragma unroll
        for (int j = 0; j < 4; ++j) {
            const float f = (&v.x)[j];
            const ushortT hb = f2bf(f);
            hi.s[j] = hb;
            lo.s[j] = f2bf(f - bf2f(hb));
        }
        *reinterpret_cast<uint2*>(&sA[n][q * 4])  = hi.u;
        *reinterpret_cast<uint2*>(&sLo[n][q * 4]) = lo.u;
    }
    // stage h16 (cols 128..255)
    for (int i = t; i < UB * 16; i += 512) {
        const int n = i >> 4, q = i & 15;
        const uint4 v = reinterpret_cast<const uint4*>(h16)[(size_t)(n0 + n) * 16 + q];
        *reinterpret_cast<uint4*>(&sA[n][128 + q * 8]) = v;
    }
    __syncthreads();

    float4v acc[4];
    #pragma unroll
    for (int m = 0; m < 4; ++m) acc[m] = (float4v)(0.f);

    const int kOff = (lane >> 4) * 8;
    #pragma unroll
    for (int m = 0; m < 4; ++m) {
        const int row = m * 16 + (lane & 15);
        #pragma unroll
        for (int kt = 0; kt < 8; ++kt) {
            const short8v a = *reinterpret_cast<const short8v*>(&sA[row][kt * 32 + kOff]);
            acc[m] = __builtin_amdgcn_mfma_f32_16x16x32_bf16(a, Bh[kt], acc[m], 0, 0, 0);
        }
        #pragma unroll
        for (int kt = 0; kt < 4; ++kt) {   // lo correction over aggr half; W rows identical
            const short8v a = *reinterpret_cast<const short8v*>(&sLo[row][kt * 32 + kOff]);
            acc[m] = __builtin_amdgcn_mfma_f32_16x16x32_bf16(a, Bh[kt], acc[m], 0, 0, 0);
        }
    }

    // epilogue: bias + relu, write bf16 raw out; per-wave column stats (exclusive cols)
    const int col  = lane & 15;
    const int r0   = (lane >> 4) * 4;
    const int ccol = ct * 16 + col;
    const float bt = bup[ccol];
    float s = 0.f, q = 0.f;
    #pragma unroll
    for (int m = 0; m < 4; ++m) {
        #pragma unroll
        for (int j = 0; j < 4; ++j) {
            const float v = fmaxf(acc[m][j] + bt, 0.f);
            s += v; q += v * v;
            hout[(size_t)(n0 + m * 16 + r0 + j) * HIDDEN + ccol] = f2bf(v);
        }
    }
    s += __shfl_xor(s, 16); s += __shfl_xor(s, 32);
    q += __shfl_xor(q, 16); q += __shfl_xor(q, 32);
    if (lane < 16) {
        p_sum  [(size_t)blockIdx.x * HIDDEN + ccol] = s;
        p_sumsq[(size_t)blockIdx.x * HIDDEN + ccol] = q;
    }
}

// ------- BN reduce: one block per feature -------
__global__ __launch_bounds__(256) void k_bn_reduce(const float* __restrict__ p_sum,
                                                   const float* __restrict__ p_sumsq,
                                                   const float* __restrict__ gamma,
                                                   const float* __restrict__ beta,
                                                   float* __restrict__ scale,
                                                   float* __restrict__ shift)
{
    const int c = blockIdx.x, t = threadIdx.x;
    float s = 0.f, q = 0.f;
    for (int i = t; i < NBLK; i += 256) {
        s += p_sum  [(size_t)i * HIDDEN + c];
        q += p_sumsq[(size_t)i * HIDDEN + c];
    }
    #pragma unroll
    for (int off = 32; off > 0; off >>= 1) {
        s += __shfl_down(s, off);
        q += __shfl_down(q, off);
    }
    __shared__ float ls[4], lq[4];
    const int w = t >> 6;
    if ((t & 63) == 0) { ls[w] = s; lq[w] = q; }
    __syncthreads();
    if (t == 0) {
        s = ls[0] + ls[1] + ls[2] + ls[3];
        q = lq[0] + lq[1] + lq[2] + lq[3];
        const float mu  = s * (1.f / N_NODES);
        const float var = q * (1.f / N_NODES) - mu * mu;
        const float sc  = gamma[c] * rsqrtf(var + BN_EPS);
        scale[c] = sc;
        shift[c] = beta[c] - mu * sc;
    }
}

// ------- mean pool over graphs (applies final BN affine inline) -------
__global__ __launch_bounds__(128) void k_pool_sum(const ushortT* __restrict__ h16,
                                                  const int* __restrict__ batch,
                                                  const float* __restrict__ scale,
                                                  const float* __restrict__ shift,
                                                  float* __restrict__ pool)
{
    const int t  = threadIdx.x;
    const int n0 = blockIdx.x * 16;
    __shared__ int sb[16];
    if (t < 16) sb[t] = batch[n0 + t];
    __syncthreads();
    const float sc = scale[t], sh = shift[t];
    int g = sb[0];
    float acc = 0.f;
    for (int j = 0; j < 16; ++j) {
        const float v = sc * bf2f(h16[(size_t)(n0 + j) * HIDDEN + t]) + sh;
        if (sb[j] != g) {
            atomicAdd(&pool[(size_t)g * HIDDEN + t], acc);
            g = sb[j];
            acc = v;
        } else {
            acc += v;
        }
    }
    atomicAdd(&pool[(size_t)g * HIDDEN + t], acc);
}

__global__ void k_pool_div(const float* __restrict__ pool,
                           const float* __restrict__ cnt,
                           float* __restrict__ out)
{
    const int i = blockIdx.x * 256 + threadIdx.x;
    if (i < N_GRAPHS * HIDDEN) {
        const int g = i >> 7;
        out[i] = pool[i] / fmaxf(cnt[g], 1.0f);
    }
}

extern "C" void kernel_launch(void* const* d_in, const int* in_sizes, int n_in,
                              void* d_out, int out_size, void* d_ws, size_t ws_size,
                              hipStream_t stream)
{
    const float* x     = (const float*)d_in[0];
    const int*   ei    = (const int*)  d_in[1];
    const float* ea    = (const float*)d_in[2];
    const int*   batch = (const int*)  d_in[3];
    const float* W_in  = (const float*)d_in[4];
    const float* b_in  = (const float*)d_in[5];
    const float* W_msg = (const float*)d_in[6];
    const float* b_msg = (const float*)d_in[7];
    const float* W_up  = (const float*)d_in[8];
    const float* b_up  = (const float*)d_in[9];
    const float* gamma = (const float*)d_in[10];
    const float* beta  = (const float*)d_in[11];
    float* out = (float*)d_out;

    // ---- workspace layout (zero-init region kept CONTIGUOUS: ecnt..cnt) ----
    float*   aggr  = (float*)d_ws;                                   // (N+1)*128 fp32 (dummy row)
    ushortT* hA    = (ushortT*)(aggr + (size_t)(N_NODES + 1) * HIDDEN);  // N*128 bf16
    ushortT* hB    = hA + (size_t)N_NODES * HIDDEN;                  // N*128 bf16
    ushortT* ea16  = hB + (size_t)N_NODES * HIDDEN;                  // (E+64)*16 bf16
    ushortT* wmsgfA = ea16 + (size_t)(N_EDGES + 64) * 16;            // 20480
    ushortT* wupfA  = wmsgfA + 20480;                                // 32768
    float*   biasM  = (float*)(wupfA + 32768);                       // 128
    float*   biasU  = biasM + HIDDEN;                                // 128
    float*   bn_scale = biasU + HIDDEN;                              // 128
    float*   bn_shift = bn_scale + HIDDEN;                           // 128
    float*   p_sum    = bn_shift + HIDDEN;                           // NBLK*128
    float*   p_sumsq  = p_sum + (size_t)HIDDEN * NBLK;               // NBLK*128
    // ---- contiguous zero-init region ----
    int*     ecnt     = (int*)(p_sumsq + (size_t)HIDDEN * NBLK);     // N
    int*     flag     = ecnt + N_NODES;                              // N+1
    int*     zcount   = flag + (N_NODES + 1);                        // 1
    float*   pool     = (float*)(zcount + 1);                        // G*128
    float*   cnt      = pool + (size_t)N_GRAPHS * HIDDEN;            // G
    // ---- end zero-init region ----
    int*     off_work = (int*)(cnt + N_GRAPHS);                      // N
    int*     bsum     = off_work + N_NODES;                          // 1024
    int*     bscan    = bsum + 1024;                                 // 1024
    int*     srcS     = bscan + 1024;                                // E+64
    int*     dstS     = srcS + (N_EDGES + 64);                       // E+64
    int*     perm     = dstS + (N_EDGES + 64);                       // E
    int*     zlist    = perm + N_EDGES;                              // N+1

    const size_t zero_bytes = ((size_t)N_NODES + (N_NODES + 1) + 1
                               + (size_t)N_GRAPHS * HIDDEN + N_GRAPHS) * 4;

    // ---- edge sort by dst + pad + needs-zero set (once; edge_index constant) ----
    hipMemsetAsync(ecnt, 0, zero_bytes, stream);   // ecnt, flag, zcount, pool, cnt
    k_hist<<<(N_EDGES + 255) / 256, 256, 0, stream>>>(ei, ecnt);
    k_chunk_sum<<<NCHUNK, 256, 0, stream>>>(ecnt, bsum);
    k_scan_bsums<<<1, 1024, 0, stream>>>(bsum, bscan);
    k_chunk_scan<<<NCHUNK, 256, 0, stream>>>(ecnt, bscan, off_work);
    k_scatter<<<(N_EDGES + 255) / 256, 256, 0, stream>>>(ei, off_work, srcS, dstS, perm);
    k_pad_edges<<<1, 1024, 0, stream>>>(srcS, dstS, ea16, bn_scale, bn_shift); // BEFORE k_flags
    k_flags<<<(FLG_ALL + 255) / 256, 256, 0, stream>>>(dstS, ecnt, flag, batch, cnt);
    k_compact<<<(N_NODES + 256) / 256, 256, 0, stream>>>(flag, zlist, zcount);

    // ---- one-time prep ----
    k_prep_ea<<<(N_EDGES * 16 + 255) / 256, 256, 0, stream>>>(ea, perm, ea16);
    k_input_mfma<<<N_NODES / 64, 512, 0, stream>>>(x, W_in, b_in, hA);

    ushortT* hcur = hA;
    ushortT* hnext = hB;
    for (int d = 0; d < DEPTH; ++d) {
        k_fold<<<466, 256, 0, stream>>>(
            W_msg + (size_t)d * (HIDDEN + EDGE_DIM) * HIDDEN, b_msg + (size_t)d * HIDDEN,
            W_up + (size_t)d * 2 * HIDDEN * HIDDEN, b_up + (size_t)d * HIDDEN,
            bn_scale, bn_shift, wmsgfA, biasM, wupfA, biasU,
            zlist, zcount, aggr);
        k_edge_mfma<<<NEBLK, 512, 0, stream>>>(
            hcur, srcS, dstS, ea16, wmsgfA, biasM, aggr);
        k_update_mfma<<<N_NODES / UB, 512, 0, stream>>>(
            aggr, hcur, wupfA, biasU, hnext, p_sum, p_sumsq);
        k_bn_reduce<<<HIDDEN, 256, 0, stream>>>(p_sum, p_sumsq,
                                                gamma + (size_t)d * HIDDEN,
                                                beta + (size_t)d * HIDDEN,
                                                bn_scale, bn_shift);
        ushortT* tmp = hcur; hcur = hnext; hnext = tmp;
    }

    k_pool_sum<<<N_NODES / 16, 128, 0, stream>>>(hcur, batch, bn_scale, bn_shift, pool);
    k_pool_div<<<(N_GRAPHS * HIDDEN + 255) / 256, 256, 0, stream>>>(pool, cnt, out);
}